// Round 7
// baseline (190.234 us; speedup 1.0000x reference)
//
#include <hip/hip_runtime.h>

// Problem constants (match reference setup_inputs)
#define BB   64
#define CIN  2048
#define COUT 2048
#define TT   128
#define NG   128      // cout groups of 16 (2 mask block-rows each)
#define NCB  256      // cin blocks of 8
#define CAPC 24       // max K64-chunks/group kept (192 slots; mean 48.6, +23 sigma)

typedef int i32x4 __attribute__((ext_vector_type(4)));

// Workspace layout (total 19,972,608 B < proven 20 MB):
//   A_blk [64][256][128][8] i8 @ 0          : spikes, cin-block-major (gatherable 1KB units)
//   Wc    [128][24][16][64] i8 @ 16 MB      : compacted masked weights per group
//   gidx  [128][192] u16       @ 19,922,944 : slot -> cin-block id (pad slots -> 0)
//   gcnt  [128] int            @ 19,972,096 : K64-chunk count per group
#define OFF_WC   16777216ull
#define OFF_GIDX 19922944ull
#define OFF_GCNT 19972096ull

// --- Prep: [0,NG) blocks do mask-scan + weight compaction; rest transpose spikes ---
__global__ void prep_kernel(const float* __restrict__ spikes,
                            const float* __restrict__ weights,
                            const float* __restrict__ mask,
                            char* __restrict__ A_blk,
                            char* __restrict__ Wc,
                            unsigned short* __restrict__ gidx,
                            int* __restrict__ gcnt) {
    __shared__ union {
        float tile[64][33];
        struct { unsigned short sidx[CAPC * 8]; int wcnt[4]; } c;
    } sm;
    int bid = blockIdx.x, tid = threadIdx.x;

    if (bid < NG) {
        // ---- group g: find nonzero cin-blocks (union of 2 mask block-rows) ----
        int g = bid;
        int lane = tid & 63, wv = tid >> 6;
        int j = tid;  // cin-block 0..255; mask is block-constant: corner test exact
        bool nz = (mask[(size_t)(16 * g) * CIN + 8 * j] != 0.f) ||
                  (mask[(size_t)(16 * g + 8) * CIN + 8 * j] != 0.f);
        unsigned long long bal = __ballot(nz);
        if (lane == 0) sm.c.wcnt[wv] = (int)__popcll(bal);
        __syncthreads();
        int cnt = sm.c.wcnt[0] + sm.c.wcnt[1] + sm.c.wcnt[2] + sm.c.wcnt[3];
        int pre = 0;
#pragma unroll
        for (int ww = 0; ww < 4; ++ww) if (ww < wv) pre += sm.c.wcnt[ww];
        int rank = pre + (int)__popcll(bal & ((1ull << lane) - 1ull));
        int nk = (cnt + 7) >> 3; if (nk > CAPC) nk = CAPC;
        int ns = nk * 8;
        if (nz && rank < ns) sm.c.sidx[rank] = (unsigned short)j;
        if (tid >= cnt && tid < ns) sm.c.sidx[tid] = 0;  // pad: block 0, zero W
        if (tid == 0) gcnt[g] = nk;
        __syncthreads();
        if (tid < ns) gidx[g * (CAPC * 8) + tid] = sm.c.sidx[tid];

        // ---- compact weights: Wc[g][s>>3][n][(s&7)*8 + jj] ----
        for (int base = 0; base < ns; base += 16) {
            int s = base + (tid >> 4);
            if (s < ns) {
                int n = tid & 15;
                int js = sm.c.sidx[s];
                // per-row mask: cout row 16g+n lies in block-row (16g+n)>>3
                bool live = (s < cnt) &&
                            (mask[(size_t)(16 * g + n) * CIN + js * 8] != 0.f);
                const float* wr = weights + (size_t)(16 * g + n) * CIN + js * 8;
                float4 w0 = *(const float4*)wr;
                float4 w1 = *(const float4*)(wr + 4);
                unsigned lo = 0, hi = 0;
                if (live) {
                    lo = ((unsigned)((char)(int)w0.x) & 0xFF)
                       | ((((unsigned)((char)(int)w0.y)) & 0xFF) << 8)
                       | ((((unsigned)((char)(int)w0.z)) & 0xFF) << 16)
                       | (((unsigned)((char)(int)w0.w)) << 24);
                    hi = ((unsigned)((char)(int)w1.x) & 0xFF)
                       | ((((unsigned)((char)(int)w1.y)) & 0xFF) << 8)
                       | ((((unsigned)((char)(int)w1.z)) & 0xFF) << 16)
                       | (((unsigned)((char)(int)w1.w)) << 24);
                }
                int2 pv; pv.x = (int)lo; pv.y = (int)hi;
                *(int2*)(Wc + ((size_t)(g * CAPC + (s >> 3)) * 16 + n) * 64 +
                         (s & 7) * 8) = pv;
            }
        }
        return;
    }

    // ---- spikes [b][c][t] f32 -> A_blk[b][cb][t][8] i8 (LDS transpose) ----
    bid -= NG;
    int cc = bid & 31;          // 64-cin tile (8 cb)
    int tt = (bid >> 5) & 3;    // 32-t tile
    int b  = bid >> 7;
    int c0 = cc * 64, t0 = tt * 32;

    int t4 = tid & 7, cr = tid >> 3;
#pragma unroll
    for (int s = 0; s < 2; ++s) {
        int c = cr + s * 32;
        float4 v = *(const float4*)(spikes + ((size_t)b * CIN + c0 + c) * TT + t0 + t4 * 4);
        sm.tile[c][t4 * 4 + 0] = v.x;
        sm.tile[c][t4 * 4 + 1] = v.y;
        sm.tile[c][t4 * 4 + 2] = v.z;
        sm.tile[c][t4 * 4 + 3] = v.w;
    }
    __syncthreads();

    int cb_l = tid >> 5;        // 0..7
    int t_l  = tid & 31;
    unsigned lo = 0, hi = 0;
#pragma unroll
    for (int jj = 0; jj < 4; ++jj)
        lo |= (sm.tile[cb_l * 8 + jj][t_l] != 0.f ? 1u : 0u) << (8 * jj);
#pragma unroll
    for (int jj = 0; jj < 4; ++jj)
        hi |= (sm.tile[cb_l * 8 + 4 + jj][t_l] != 0.f ? 1u : 0u) << (8 * jj);
    int2 pv; pv.x = (int)lo; pv.y = (int)hi;
    *(int2*)(A_blk + ((size_t)((b * NCB + cc * 8 + cb_l) * TT) + t0 + t_l) * 8) = pv;
}

// --- Main: block-sparse GEMM + LIF scan. One wave per (b, 16-cout group).
//     No barriers: waves stream gathered A (1KB blocks) + compacted B from
//     L1/L2 straight into mfma_i32_16x16x64_i8, then wave-private LDS
//     transpose (pad 18 -> 2-way = free) + scan + coalesced stores. ---
__global__ void __launch_bounds__(256, 4)
snn_sparse(const char* __restrict__ A_blk,
           const char* __restrict__ Wc,
           const unsigned short* __restrict__ gidx,
           const int* __restrict__ gcnt,
           const int* __restrict__ scale_exp,
           const int* __restrict__ thr_exp,
           float* __restrict__ out) {
    __shared__ float ldsC[4][TT * 18];   // 36,864 B -> 4 blocks/CU

    const int tid = threadIdx.x, lane = tid & 63, wv = tid >> 6;
    const int bid = blockIdx.x;
    const int b = bid >> 5, q = bid & 31;
    const int g = q * 4 + wv;

    const int nk = gcnt[g];
    const unsigned short* idx = gidx + g * (CAPC * 8);
    const char* wcg = Wc + (size_t)g * CAPC * 1024;
    const char* ab  = A_blk + (size_t)b * (NCB * TT * 8);

    const int m  = lane & 15;   // A-row (t within 16-tile) == B-col (cout) == C-col
    const int kq = lane >> 4;   // k-quad

    i32x4 acc[8] = {};
    for (int ck = 0; ck < nk; ++ck) {
        unsigned pair = *(const unsigned*)(idx + ck * 8 + kq * 2);
        unsigned s0 = pair & 0xFFFFu, s1 = pair >> 16;
        i32x4 bfrag = *(const i32x4*)(wcg + ck * 1024 + m * 64 + kq * 16);
        const char* a0p = ab + ((size_t)s0 << 10) + m * 8;
        const char* a1p = ab + ((size_t)s1 << 10) + m * 8;
#pragma unroll
        for (int mt = 0; mt < 8; ++mt) {
            int2 a0 = *(const int2*)(a0p + mt * 128);
            int2 a1 = *(const int2*)(a1p + mt * 128);
            i32x4 af; af[0] = a0.x; af[1] = a0.y; af[2] = a1.x; af[3] = a1.y;
            acc[mt] = __builtin_amdgcn_mfma_i32_16x16x64_i8(af, bfrag, acc[mt], 0, 0, 0);
        }
    }

    // C (col=lane&15 -> cout, row=kq*4+reg -> t) -> wave-private LDS [t][cout]
    float* lc = ldsC[wv];
#pragma unroll
    for (int mt = 0; mt < 8; ++mt)
#pragma unroll
        for (int r = 0; r < 4; ++r)
            lc[(mt * 16 + kq * 4 + r) * 18 + m] = (float)acc[mt][r];

    // all 64 lanes scan cout=m (4x redundant -> LDS broadcast, no divergence)
    const float scale = exp2f((float)scale_exp[g * 16 + m]);
    const float thr   = exp2f((float)thr_exp[0]);
    float a = 0.f;
    unsigned bits[4] = {0u, 0u, 0u, 0u};
#pragma unroll 4
    for (int t = 0; t < TT; ++t) {
        a += lc[t * 18 + m] * scale;
        unsigned s = (a >= thr) ? 1u : 0u;
        if (s) a = 0.f;
        bits[t >> 5] |= s << (t & 31);
    }

    // lane stores quarter kq of cout m: out[b][g*16+m][kq*32 .. +32]
    unsigned wb = bits[kq];
    float* op = out + ((size_t)(b * COUT + g * 16 + m)) * TT + kq * 32;
#pragma unroll
    for (int s2 = 0; s2 < 8; ++s2) {
        unsigned nib = (wb >> (s2 * 4)) & 0xFu;
        float4 v;
        v.x = (float)(nib & 1u);
        v.y = (float)((nib >> 1) & 1u);
        v.z = (float)((nib >> 2) & 1u);
        v.w = (float)((nib >> 3) & 1u);
        *(float4*)(op + s2 * 4) = v;
    }
}

extern "C" void kernel_launch(void* const* d_in, const int* in_sizes, int n_in,
                              void* d_out, int out_size, void* d_ws, size_t ws_size,
                              hipStream_t stream) {
    const float* spikes  = (const float*)d_in[0];
    const float* weights = (const float*)d_in[1];
    const float* mask    = (const float*)d_in[2];
    const int*   scale_e = (const int*)d_in[3];
    const int*   thr_e   = (const int*)d_in[4];
    float* out = (float*)d_out;

    char* A_blk = (char*)d_ws;
    char* Wc    = (char*)d_ws + OFF_WC;
    unsigned short* gidx = (unsigned short*)((char*)d_ws + OFF_GIDX);
    int* gcnt = (int*)((char*)d_ws + OFF_GCNT);

    prep_kernel<<<NG + BB * 4 * 32, 256, 0, stream>>>(spikes, weights, mask,
                                                      A_blk, Wc, gidx, gcnt);
    snn_sparse<<<BB * 32, 256, 0, stream>>>(A_blk, Wc, gidx, gcnt,
                                            scale_e, thr_e, out);
}